// Round 9
// baseline (312.215 us; speedup 1.0000x reference)
//
#include <hip/hip_runtime.h>
#include <hip/hip_bf16.h>
#include <hip/hip_cooperative_groups.h>

namespace cg = cooperative_groups;

#define B_NUM 2
#define T_SEQ 2048
#define C_DIM 1024
#define H_NUM 16
#define HD    64
#define M_TOT 4096
#define BH_N  32

typedef __attribute__((ext_vector_type(8))) short short8;   // 8 bf16
typedef __attribute__((ext_vector_type(4))) float floatx4;  // 4 fp32 acc

__device__ __forceinline__ short f2bf(float f) {
    unsigned u = __float_as_uint(f);
    u += 0x7FFFu + ((u >> 16) & 1u);
    return (short)(u >> 16);
}

__device__ __forceinline__ unsigned pk2bf(float a, float b) {
    float2 f2; f2.x = a; f2.y = b;
    __hip_bfloat162 h = __float22bfloat162_rn(f2);
    unsigned u; __builtin_memcpy(&u, &h, 4); return u;
}

// async global->LDS, 16B per lane; LDS dest = wave-uniform base + lane*16
__device__ __forceinline__ void gld16(const short* g, short* l) {
    __builtin_amdgcn_global_load_lds(
        (const __attribute__((address_space(1))) void*)g,
        (__attribute__((address_space(3))) void*)l, 16, 0, 0);
}

// ===========================================================================
// Cooperative mega-kernel (grid-stride phases; works for any grid size).
// ===========================================================================
__global__ __launch_bounds__(512, 4) void mega(
    const float* __restrict__ x,  const float* __restrict__ Wq,
    const float* __restrict__ Wk, const float* __restrict__ Wv,
    const float* __restrict__ Wp, const float* __restrict__ bp,
    short* __restrict__ xb, short* __restrict__ wt, short* __restrict__ wpt,
    short* __restrict__ qb, short* __restrict__ kb, short* __restrict__ vtb,
    short* __restrict__ attb, float* __restrict__ out) {

    __shared__ short smem[26112];            // 52224 B, max over phases
    cg::grid_group grid = cg::this_grid();

    const int G   = gridDim.x;
    const int bid = blockIdx.x;
    const int tid = threadIdx.x;
    const int lane = tid & 63, w = tid >> 6;           // 8 waves
    const int hi = lane >> 4, llo = lane & 15;
    const int lrow = lane >> 3;
    const int lswz = ((lane & 7) ^ (lrow & 7)) * 8;
    const int fc0 = (hi ^ (llo & 7)) * 8;
    const int fc1 = ((hi + 4) ^ (llo & 7)) * 8;

    // ============================ Phase 0: prep ============================
    {
        int gtid = bid * 512 + tid;
        for (int i = gtid; i < 524288; i += G * 512) {
            int idx = i * 8;
            float4 a = *(const float4*)(x + idx);
            float4 b4 = *(const float4*)(x + idx + 4);
            short8 o;
            o[0] = f2bf(a.x);  o[1] = f2bf(a.y);  o[2] = f2bf(a.z);  o[3] = f2bf(a.w);
            o[4] = f2bf(b4.x); o[5] = f2bf(b4.y); o[6] = f2bf(b4.z); o[7] = f2bf(b4.w);
            *(short8*)(xb + idx) = o;
        }
        short (*sh)[72] = (short(*)[72])smem;
        for (int unit = bid; unit < 1024; unit += G) {
            __syncthreads();
            if (unit < 768) {
                const int y = unit >> 4, ct = unit & 15;
                const int which = y >> 4, h = y & 15;
                const float* W = ((which == 0) ? Wq : (which == 1) ? Wk : Wv)
                                 + (size_t)h * C_DIM * HD;
                const int c0 = ct * 64;
                #pragma unroll
                for (int p = 0; p < 2; ++p) {
                    int idx = tid + 512 * p;
                    int c = idx >> 4, d4 = idx & 15;
                    float4 v = *(const float4*)(W + (size_t)(c0 + c) * HD + d4 * 4);
                    sh[d4 * 4 + 0][c] = f2bf(v.x);
                    sh[d4 * 4 + 1][c] = f2bf(v.y);
                    sh[d4 * 4 + 2][c] = f2bf(v.z);
                    sh[d4 * 4 + 3][c] = f2bf(v.w);
                }
                __syncthreads();
                int d = tid >> 3, cc = tid & 7;
                short8 vv = *(const short8*)(&sh[d][cc * 8]);
                *(short8*)(wt + ((size_t)(which * 16 + h) * 64 + d) * C_DIM + c0 + cc * 8) = vv;
            } else {
                const int u2 = unit - 768;
                const int nt = u2 >> 4, ct = u2 & 15;
                #pragma unroll
                for (int p = 0; p < 2; ++p) {
                    int idx = tid + 512 * p;
                    int k = idx >> 4, n4 = idx & 15;
                    float4 v = *(const float4*)(Wp + (size_t)(ct * 64 + k) * C_DIM + nt * 64 + n4 * 4);
                    sh[n4 * 4 + 0][k] = f2bf(v.x);
                    sh[n4 * 4 + 1][k] = f2bf(v.y);
                    sh[n4 * 4 + 2][k] = f2bf(v.z);
                    sh[n4 * 4 + 3][k] = f2bf(v.w);
                }
                __syncthreads();
                int n = tid >> 3, cc = tid & 7;
                short8 vv = *(const short8*)(&sh[n][cc * 8]);
                *(short8*)(wpt + (size_t)(nt * 64 + n) * C_DIM + ct * 64 + cc * 8) = vv;
            }
        }
    }
    grid.sync();

    // ============================ Phase 1: qkv =============================
    // C[4096 x 3072] = xb * wt^T. 512 tiles of 128 x 192, BK=64.
    for (int tile = bid; tile < 512; tile += G) {
        const int mt = tile >> 4, ntg = tile & 15;
        const int m0 = mt * 128, n0 = ntg * 192;
        const int wm = w & 1, wn = w >> 1;
        short* As = smem;                    // [128][64] swizzled
        short* Bs = smem + 8192;             // [192][64] swizzled

        floatx4 acc[4][3];
        #pragma unroll
        for (int i = 0; i < 4; ++i)
            #pragma unroll
            for (int j = 0; j < 3; ++j)
                #pragma unroll
                for (int r = 0; r < 4; ++r) acc[i][j][r] = 0.0f;

        const size_t a_base = (size_t)(m0 + w * 16 + lrow) * C_DIM + lswz;
        const size_t b_base = (size_t)(n0 + w * 24 + lrow) * C_DIM + lswz;

        for (int kt = 0; kt < C_DIM / 64; ++kt) {
            const int c0 = kt * 64;
            __syncthreads();
            #pragma unroll
            for (int p = 0; p < 2; ++p)
                gld16(xb + a_base + (size_t)p * 8 * C_DIM + c0, &As[(w * 16 + p * 8) * 64]);
            #pragma unroll
            for (int p = 0; p < 3; ++p)
                gld16(wt + b_base + (size_t)p * 8 * C_DIM + c0, &Bs[(w * 24 + p * 8) * 64]);
            __syncthreads();

            short8 af[4][2];
            #pragma unroll
            for (int mi = 0; mi < 4; ++mi) {
                const int row = wm * 64 + mi * 16 + llo;
                af[mi][0] = *(const short8*)(&As[row * 64 + fc0]);
                af[mi][1] = *(const short8*)(&As[row * 64 + fc1]);
            }
            #pragma unroll
            for (int ni = 0; ni < 3; ++ni) {
                const int row = wn * 48 + ni * 16 + llo;
                short8 b0 = *(const short8*)(&Bs[row * 64 + fc0]);
                short8 b1 = *(const short8*)(&Bs[row * 64 + fc1]);
                #pragma unroll
                for (int mi = 0; mi < 4; ++mi) {
                    acc[mi][ni] = __builtin_amdgcn_mfma_f32_16x16x32_bf16(af[mi][0], b0, acc[mi][ni], 0, 0, 0);
                    acc[mi][ni] = __builtin_amdgcn_mfma_f32_16x16x32_bf16(af[mi][1], b1, acc[mi][ni], 0, 0, 0);
                }
            }
        }

        const int bb = m0 >> 11;
        #pragma unroll
        for (int c = 0; c < 3; ++c) {
            const int n_chunk = n0 + 64 * c;
            const int which = n_chunk >> 10;
            const int h = (n_chunk >> 6) & 15;
            __syncthreads();
            if (which == 2) {
                short (*R)[136] = (short(*)[136])smem;
                #pragma unroll
                for (int ni = 0; ni < 3; ++ni) {
                    const int gcol = wn * 48 + ni * 16;
                    if ((gcol >> 6) == c) {
                        #pragma unroll
                        for (int mi = 0; mi < 4; ++mi)
                            #pragma unroll
                            for (int r = 0; r < 4; ++r)
                                R[(gcol & 63) + llo][wm * 64 + mi * 16 + hi * 4 + r] =
                                    f2bf(acc[mi][ni][r]);
                    }
                }
                __syncthreads();
                #pragma unroll
                for (int p = 0; p < 2; ++p) {
                    int idx = tid + 512 * p;
                    int rr = idx >> 4, cc = idx & 15;
                    short8 vv = *(const short8*)(&R[rr][cc * 8]);
                    int t = (m0 & 2047) + cc * 8;
                    *(short8*)(vtb + ((size_t)((bb * H_NUM + h) * HD + rr)) * T_SEQ + t) = vv;
                }
            } else {
                short (*R)[72] = (short(*)[72])smem;
                const float scl = (which == 0) ? 0.125f * 1.4426950408889634f : 1.0f;
                #pragma unroll
                for (int ni = 0; ni < 3; ++ni) {
                    const int gcol = wn * 48 + ni * 16;
                    if ((gcol >> 6) == c) {
                        #pragma unroll
                        for (int mi = 0; mi < 4; ++mi)
                            #pragma unroll
                            for (int r = 0; r < 4; ++r)
                                R[wm * 64 + mi * 16 + hi * 4 + r][(gcol & 63) + llo] =
                                    f2bf(acc[mi][ni][r] * scl);
                    }
                }
                __syncthreads();
                short* outp = (which == 0) ? qb : kb;
                #pragma unroll
                for (int p = 0; p < 2; ++p) {
                    int idx = tid + 512 * p;
                    int r = idx >> 3, cc = idx & 7;
                    short8 vv = *(const short8*)(&R[r][cc * 8]);
                    int t = (m0 + r) & 2047;
                    *(short8*)(outp + ((size_t)(bb * H_NUM + h) * T_SEQ + t) * HD + cc * 8) = vv;
                }
            }
        }
    }
    grid.sync();

    // ============================ Phase 2: attn ============================
    for (int unit = bid; unit < 512; unit += G) {
        const int bh = unit & 31;
        const int y = unit >> 5;
        const int qt = (y < 8) ? (15 - y) : (y - 8);
        const int b = bh >> 4, h = bh & 15;
        const short* K  = kb  + (size_t)bh * T_SEQ * HD;
        const short* Vt = vtb + (size_t)bh * HD * T_SEQ;

        short* Ks = smem;                    // [2][64][64] swizzled (8192 shorts)
        short* Vs = smem + 8192;
        short (*Ps)[76] = (short(*)[76])(smem + 16384);  // [128][76]

        const int kmax = 2 * qt + 1;

        short8 qf[2];
        const int qcol0 = qt * 128 + w * 16;
        #pragma unroll
        for (int kh = 0; kh < 2; ++kh)
            qf[kh] = *(const short8*)(qb +
                ((size_t)bh * T_SEQ + qcol0 + llo) * HD + kh * 32 + hi * 8);

        short8 av4;                          // ones-row A-frag
        #pragma unroll
        for (int j = 0; j < 8; ++j) av4[j] = (llo == 0) ? (short)0x3F80 : (short)0;

        gld16(K + (size_t)(w * 8 + lrow) * HD + lswz, &Ks[(w * 8) * 64]);
        gld16(Vt + (size_t)(w * 8 + lrow) * T_SEQ + lswz, &Vs[(w * 8) * 64]);

        floatx4 Oa[5];
        #pragma unroll
        for (int n = 0; n < 5; ++n)
            #pragma unroll
            for (int r = 0; r < 4; ++r) Oa[n][r] = 0.0f;

        for (int kt = 0; kt <= kmax; ++kt) {
            __syncthreads();
            const int buf = (kt & 1) * 4096;

            if (kt + 1 <= kmax) {
                const int s0 = (kt + 1) * 64;
                const int nb = ((kt + 1) & 1) * 4096;
                gld16(K + ((size_t)s0 + w * 8 + lrow) * HD + lswz, &Ks[nb + (w * 8) * 64]);
                gld16(Vt + (size_t)(w * 8 + lrow) * T_SEQ + s0 + lswz, &Vs[nb + (w * 8) * 64]);
            }

            short8 ak[4][2];
            #pragma unroll
            for (int nt = 0; nt < 4; ++nt) {
                const int row = nt * 16 + llo;
                ak[nt][0] = *(const short8*)(&Ks[buf + row * 64 + fc0]);
                ak[nt][1] = *(const short8*)(&Ks[buf + row * 64 + fc1]);
            }
            floatx4 sf[4];
            #pragma unroll
            for (int nt = 0; nt < 4; ++nt)
                #pragma unroll
                for (int r = 0; r < 4; ++r) sf[nt][r] = 0.0f;
            #pragma unroll
            for (int nt = 0; nt < 4; ++nt)
                #pragma unroll
                for (int kh = 0; kh < 2; ++kh)
                    sf[nt] = __builtin_amdgcn_mfma_f32_16x16x32_bf16(
                        ak[nt][kh], qf[kh], sf[nt], 0, 0, 0);

            const int sbase = kt * 64;
            if (sbase + 63 > qcol0) {
                const int qlane = qcol0 + llo;
                #pragma unroll
                for (int nt = 0; nt < 4; ++nt)
                    #pragma unroll
                    for (int r = 0; r < 4; ++r)
                        if (sbase + nt * 16 + hi * 4 + r > qlane) sf[nt][r] = -3.0e38f;
            }

            #pragma unroll
            for (int nt = 0; nt < 4; ++nt) {
                float p0 = __builtin_amdgcn_exp2f(sf[nt][0]);
                float p1 = __builtin_amdgcn_exp2f(sf[nt][1]);
                float p2 = __builtin_amdgcn_exp2f(sf[nt][2]);
                float p3 = __builtin_amdgcn_exp2f(sf[nt][3]);
                uint2 u; u.x = pk2bf(p0, p1); u.y = pk2bf(p2, p3);
                *(uint2*)(&Ps[w * 16 + llo][nt * 16 + hi * 4]) = u;
            }

            short8 av[5][2];
            #pragma unroll
            for (int nt2 = 0; nt2 < 4; ++nt2) {
                const int row = nt2 * 16 + llo;
                av[nt2][0] = *(const short8*)(&Vs[buf + row * 64 + fc0]);
                av[nt2][1] = *(const short8*)(&Vs[buf + row * 64 + fc1]);
            }
            av[4][0] = av4;
            av[4][1] = av4;
            short8 bpf[2];
            #pragma unroll
            for (int kh = 0; kh < 2; ++kh)
                bpf[kh] = *(const short8*)(&Ps[w * 16 + llo][kh * 32 + hi * 8]);
            #pragma unroll
            for (int nt2 = 0; nt2 < 5; ++nt2)
                #pragma unroll
                for (int kh = 0; kh < 2; ++kh)
                    Oa[nt2] = __builtin_amdgcn_mfma_f32_16x16x32_bf16(
                        av[nt2][kh], bpf[kh], Oa[nt2], 0, 0, 0);
        }

        {
            float lb = __shfl(Oa[4][0], llo);
            float inv = 1.0f / lb;
            #pragma unroll
            for (int nt2 = 0; nt2 < 4; ++nt2) {
                uint2 u;
                u.x = pk2bf(Oa[nt2][0] * inv, Oa[nt2][1] * inv);
                u.y = pk2bf(Oa[nt2][2] * inv, Oa[nt2][3] * inv);
                *(uint2*)(&Ps[w * 16 + llo][nt2 * 16 + hi * 4]) = u;
            }
        }
        __syncthreads();
        #pragma unroll
        for (int p = 0; p < 2; ++p) {
            int idx = tid + 512 * p;
            int r = idx >> 3, cc = idx & 7;
            short8 vv = *(const short8*)(&Ps[r][cc * 8]);
            *(short8*)(attb + ((size_t)(b * T_SEQ + qt * 128 + r)) * C_DIM + h * HD + cc * 8) = vv;
        }
        __syncthreads();
    }
    grid.sync();

    // ============================ Phase 3: proj ============================
    for (int tile = bid; tile < 512; tile += G) {
        const int mt = tile >> 4, ntg = tile & 15;
        const int m0 = mt * 128, n0 = ntg * 64;
        const int wm = w & 1, wn = w >> 1;
        short* As = smem;                    // [128][64] swizzled
        short* Bs = smem + 8192;             // [64][64]  swizzled

        floatx4 acc[4];
        #pragma unroll
        for (int i = 0; i < 4; ++i)
            #pragma unroll
            for (int r = 0; r < 4; ++r) acc[i][r] = 0.0f;

        const size_t a_base = (size_t)(m0 + w * 16 + lrow) * C_DIM + lswz;
        const size_t b_base = (size_t)(n0 + w * 8 + lrow) * C_DIM + lswz;

        for (int kt = 0; kt < C_DIM / 64; ++kt) {
            const int c0 = kt * 64;
            __syncthreads();
            #pragma unroll
            for (int p = 0; p < 2; ++p)
                gld16(attb + a_base + (size_t)p * 8 * C_DIM + c0, &As[(w * 16 + p * 8) * 64]);
            gld16(wpt + b_base + c0, &Bs[(w * 8) * 64]);
            __syncthreads();

            short8 af[4][2];
            #pragma unroll
            for (int mi = 0; mi < 4; ++mi) {
                const int row = wm * 64 + mi * 16 + llo;
                af[mi][0] = *(const short8*)(&As[row * 64 + fc0]);
                af[mi][1] = *(const short8*)(&As[row * 64 + fc1]);
            }
            const int brow = wn * 16 + llo;
            short8 b0 = *(const short8*)(&Bs[brow * 64 + fc0]);
            short8 b1 = *(const short8*)(&Bs[brow * 64 + fc1]);
            #pragma unroll
            for (int mi = 0; mi < 4; ++mi) {
                acc[mi] = __builtin_amdgcn_mfma_f32_16x16x32_bf16(af[mi][0], b0, acc[mi], 0, 0, 0);
                acc[mi] = __builtin_amdgcn_mfma_f32_16x16x32_bf16(af[mi][1], b1, acc[mi], 0, 0, 0);
            }
        }

        const int n = n0 + wn * 16 + llo;
        const float bias = bp[n];
        #pragma unroll
        for (int mi = 0; mi < 4; ++mi)
            #pragma unroll
            for (int r = 0; r < 4; ++r) {
                int m = m0 + wm * 64 + mi * 16 + hi * 4 + r;
                out[(size_t)m * C_DIM + n] = acc[mi][r] + bias;
            }
        __syncthreads();
    }
}

// ===========================================================================
// Fallback path: round-6 four-kernel pipeline (known-good, ~179 us).
// ===========================================================================
__global__ __launch_bounds__(256) void prep_k(
    const float* __restrict__ x, const float* __restrict__ Wq,
    const float* __restrict__ Wk, const float* __restrict__ Wv,
    const float* __restrict__ Wp,
    short* __restrict__ xb, short* __restrict__ wt, short* __restrict__ wpt) {
    const int bid = blockIdx.x;
    const int tid = threadIdx.x;
    if (bid < 2048) {
        int idx = (bid * 256 + tid) * 8;
        float4 a = *(const float4*)(x + idx);
        float4 b = *(const float4*)(x + idx + 4);
        short8 o;
        o[0] = f2bf(a.x); o[1] = f2bf(a.y); o[2] = f2bf(a.z); o[3] = f2bf(a.w);
        o[4] = f2bf(b.x); o[5] = f2bf(b.y); o[6] = f2bf(b.z); o[7] = f2bf(b.w);
        *(short8*)(xb + idx) = o;
        return;
    }
    const int b2 = bid - 2048;
    const int ct = b2 & 15, y = b2 >> 4;
    __shared__ short sh[64][72];
    if (y < 48) {
        const int which = y >> 4, h = y & 15;
        const float* W = ((which == 0) ? Wq : (which == 1) ? Wk : Wv) + (size_t)h * C_DIM * HD;
        const int c0 = ct * 64;
        #pragma unroll
        for (int p = 0; p < 4; ++p) {
            int idx = tid + 256 * p;
            int c = idx >> 4, d4 = idx & 15;
            float4 v = *(const float4*)(W + (size_t)(c0 + c) * HD + d4 * 4);
            sh[d4 * 4 + 0][c] = f2bf(v.x);
            sh[d4 * 4 + 1][c] = f2bf(v.y);
            sh[d4 * 4 + 2][c] = f2bf(v.z);
            sh[d4 * 4 + 3][c] = f2bf(v.w);
        }
        __syncthreads();
        #pragma unroll
        for (int p = 0; p < 2; ++p) {
            int idx = tid + 256 * p;
            int d = idx >> 3, cc = idx & 7;
            short8 vv = *(const short8*)(&sh[d][cc * 8]);
            *(short8*)(wt + ((size_t)(which * 16 + h) * 64 + d) * C_DIM + c0 + cc * 8) = vv;
        }
    } else {
        const int nt = y - 48;
        #pragma unroll
        for (int p = 0; p < 4; ++p) {
            int idx = tid + 256 * p;
            int k = idx >> 4, n4 = idx & 15;
            float4 v = *(const float4*)(Wp + (size_t)(ct * 64 + k) * C_DIM + nt * 64 + n4 * 4);
            sh[n4 * 4 + 0][k] = f2bf(v.x);
            sh[n4 * 4 + 1][k] = f2bf(v.y);
            sh[n4 * 4 + 2][k] = f2bf(v.z);
            sh[n4 * 4 + 3][k] = f2bf(v.w);
        }
        __syncthreads();
        #pragma unroll
        for (int p = 0; p < 2; ++p) {
            int idx = tid + 256 * p;
            int n = idx >> 3, cc = idx & 7;
            short8 vv = *(const short8*)(&sh[n][cc * 8]);
            *(short8*)(wpt + (size_t)(nt * 64 + n) * C_DIM + ct * 64 + cc * 8) = vv;
        }
    }
}

__global__ __launch_bounds__(256) void qkv_k(
    const short* __restrict__ xb, const short* __restrict__ wt,
    short* __restrict__ qb, short* __restrict__ kb, short* __restrict__ vtb) {
    const int mt = blockIdx.x, ntg = blockIdx.y;
    const int m0 = mt * 128, n0 = ntg * 128;
    const int which = ntg >> 3;
    const float sc = (which == 0) ? 0.125f * 1.4426950408889634f : 1.0f;

    __shared__ short smem[17408];
    short* As = smem;
    short* Bs = smem + 8192;

    const int tid = threadIdx.x;
    const int lane = tid & 63, w = tid >> 6;
    const int wm = w & 1, wn = w >> 1;
    const int hi = lane >> 4, llo = lane & 15;
    const int lrow = lane >> 3;
    const int lswz = ((lane & 7) ^ (lrow & 7)) * 8;
    const int fc0 = (hi ^ (llo & 7)) * 8;
    const int fc1 = ((hi + 4) ^ (llo & 7)) * 8;

    floatx4 acc[4][4];
    #pragma unroll
    for (int i = 0; i < 4; ++i)
        #pragma unroll
        for (int j = 0; j < 4; ++j)
            #pragma unroll
            for (int r = 0; r < 4; ++r) acc[i][j][r] = 0.0f;

    const size_t a_base = (size_t)(m0 + w * 32 + lrow) * C_DIM + lswz;
    const size_t b_base = (size_t)(n0 + w * 32 + lrow) * C_DIM + lswz;

    for (int kt = 0; kt < C_DIM / 64; ++kt) {
        const int c0 = kt * 64;
        __syncthreads();
        #pragma unroll
        for (int p = 0; p < 4; ++p) {
            gld16(xb + a_base + (size_t)p * 8 * C_DIM + c0, &As[(w * 32 + p * 8) * 64]);
            gld16(wt + b_base + (size_t)p * 8 * C_DIM + c0, &Bs[(w * 32 + p * 8) * 64]);
        }
        __syncthreads();

        short8 af[4][2];
        #pragma unroll
        for (int mi = 0; mi < 4; ++mi) {
            const int row = wm * 64 + mi * 16 + llo;
            af[mi][0] = *(const short8*)(&As[row * 64 + fc0]);
            af[mi][1] = *(const short8*)(&As[row * 64 + fc1]);
        }
        #pragma unroll
        for (int ni = 0; ni < 4; ++ni) {
            const int row = wn * 64 + ni * 16 + llo;
            short8 b0 = *(const short8*)(&Bs[row * 64 + fc0]);
            short8 b1 = *(const short8*)(&Bs[row * 64 + fc1]);
            #pragma unroll
            for (int mi = 0; mi < 4; ++mi) {
                acc[mi][ni] = __builtin_amdgcn_mfma_f32_16x16x32_bf16(af[mi][0], b0, acc[mi][ni], 0, 0, 0);
                acc[mi][ni] = __builtin_amdgcn_mfma_f32_16x16x32_bf16(af[mi][1], b1, acc[mi][ni], 0, 0, 0);
            }
        }
    }
    __syncthreads();

    short (*R)[136] = (short(*)[136])smem;
    if (which == 2) {
        #pragma unroll
        for (int mi = 0; mi < 4; ++mi)
            #pragma unroll
            for (int ni = 0; ni < 4; ++ni)
                #pragma unroll
                for (int r = 0; r < 4; ++r)
                    R[wn * 64 + ni * 16 + llo][wm * 64 + mi * 16 + hi * 4 + r] =
                        f2bf(acc[mi][ni][r]);
        __syncthreads();
        const int b = m0 >> 11;
        #pragma unroll
        for (int p = 0; p < 8; ++p) {
            int idx = tid + 256 * p;
            int rr = idx >> 4, cc = idx & 15;
            short8 vv = *(const short8*)(&R[rr][cc * 8]);
            int n = n0 + rr;
            int h = (n >> 6) & 15, d = n & 63;
            int t = (m0 & 2047) + cc * 8;
            *(short8*)(vtb + ((size_t)((b * H_NUM + h) * HD + d)) * T_SEQ + t) = vv;
        }
    } else {
        short* outp = (which == 0) ? qb : kb;
        #pragma unroll
        for (int mi = 0; mi < 4; ++mi)
            #pragma unroll
            for (int ni = 0; ni < 4; ++ni)
                #pragma unroll
                for (int r = 0; r < 4; ++r)
                    R[wm * 64 + mi * 16 + hi * 4 + r][wn * 64 + ni * 16 + llo] =
                        f2bf(acc[mi][ni][r] * sc);
        __syncthreads();
        #pragma unroll
        for (int p = 0; p < 8; ++p) {
            int idx = tid + 256 * p;
            int r = idx >> 4, cc = idx & 15;
            short8 vv = *(const short8*)(&R[r][cc * 8]);
            int mg = m0 + r;
            int b = mg >> 11, t = mg & 2047;
            int n = n0 + cc * 8;
            int h = (n >> 6) & 15, d = n & 63;
            *(short8*)(outp + ((size_t)(b * H_NUM + h) * T_SEQ + t) * HD + d) = vv;
        }
    }
}

__global__ __launch_bounds__(512) void attn_k(
    const short* __restrict__ qb, const short* __restrict__ kb,
    const short* __restrict__ vtb, short* __restrict__ attb) {
    const int bh = blockIdx.x;
    const int y = blockIdx.y;
    const int qt = (y < 8) ? (15 - y) : (y - 8);
    const int b = bh >> 4, h = bh & 15;
    const short* K  = kb  + (size_t)bh * T_SEQ * HD;
    const short* Vt = vtb + (size_t)bh * HD * T_SEQ;

    __shared__ short Ks[2][4096];
    __shared__ short Vs[2][4096];
    __shared__ short Ones[16 * 64];
    __shared__ short Ps[128][76];

    const int tid = threadIdx.x;
    const int lane = tid & 63, w = tid >> 6;
    const int hi = lane >> 4, llo = lane & 15;
    const int lrow = lane >> 3;
    const int lswz = ((lane & 7) ^ (lrow & 7)) * 8;
    const int fc0 = (hi ^ (llo & 7)) * 8;
    const int fc1 = ((hi + 4) ^ (llo & 7)) * 8;
    const int kmax = 2 * qt + 1;

    short8 qf[2];
    const int qcol0 = qt * 128 + w * 16;
    #pragma unroll
    for (int kh = 0; kh < 2; ++kh)
        qf[kh] = *(const short8*)(qb +
            ((size_t)bh * T_SEQ + qcol0 + llo) * HD + kh * 32 + hi * 8);

    for (int i = tid; i < 16 * 64; i += 512)
        Ones[i] = (i < 64) ? (short)0x3F80 : (short)0;

    gld16(K + (size_t)(w * 8 + lrow) * HD + lswz, &Ks[0][(w * 8) * 64]);
    gld16(Vt + (size_t)(w * 8 + lrow) * T_SEQ + lswz, &Vs[0][(w * 8) * 64]);

    floatx4 Oa[5];
    #pragma unroll
    for (int n = 0; n < 5; ++n)
        #pragma unroll
        for (int r = 0; r < 4; ++r) Oa[n][r] = 0.0f;

    for (int kt = 0; kt <= kmax; ++kt) {
        __syncthreads();
        const int buf = kt & 1;

        if (kt + 1 <= kmax) {
            const int s0 = (kt + 1) * 64;
            const int nb = buf ^ 1;
            gld16(K + ((size_t)s0 + w * 8 + lrow) * HD + lswz, &Ks[nb][(w * 8) * 64]);
            gld16(Vt + (size_t)(w * 8 + lrow) * T_SEQ + s0 + lswz, &Vs[nb][(w * 8) * 64]);
        }

        short8 ak[4][2];
        #pragma unroll
        for (int nt = 0; nt < 4; ++nt) {
            const int row = nt * 16 + llo;
            ak[nt][0] = *(const short8*)(&Ks[buf][row * 64 + fc0]);
            ak[nt][1] = *(const short8*)(&Ks[buf][row * 64 + fc1]);
        }
        floatx4 sf[4];
        #pragma unroll
        for (int nt = 0; nt < 4; ++nt)
            #pragma unroll
            for (int r = 0; r < 4; ++r) sf[nt][r] = 0.0f;
        #pragma unroll
        for (int nt = 0; nt < 4; ++nt)
            #pragma unroll
            for (int kh = 0; kh < 2; ++kh)
                sf[nt] = __builtin_amdgcn_mfma_f32_16x16x32_bf16(
                    ak[nt][kh], qf[kh], sf[nt], 0, 0, 0);

        const int sbase = kt * 64;
        if (sbase + 63 > qcol0) {
            const int qlane = qcol0 + llo;
            #pragma unroll
            for (int nt = 0; nt < 4; ++nt)
                #pragma unroll
                for (int r = 0; r < 4; ++r)
                    if (sbase + nt * 16 + hi * 4 + r > qlane) sf[nt][r] = -3.0e38f;
        }

        #pragma unroll
        for (int nt = 0; nt < 4; ++nt) {
            float p0 = __builtin_amdgcn_exp2f(sf[nt][0]);
            float p1 = __builtin_amdgcn_exp2f(sf[nt][1]);
            float p2 = __builtin_amdgcn_exp2f(sf[nt][2]);
            float p3 = __builtin_amdgcn_exp2f(sf[nt][3]);
            uint2 u; u.x = pk2bf(p0, p1); u.y = pk2bf(p2, p3);
            *(uint2*)(&Ps[w * 16 + llo][nt * 16 + hi * 4]) = u;
        }

        short8 av[5][2];
        #pragma unroll
        for (int nt2 = 0; nt2 < 4; ++nt2) {
            const int row = nt2 * 16 + llo;
            av[nt2][0] = *(const short8*)(&Vs[buf][row * 64 + fc0]);
            av[nt2][1] = *(const short8*)(&Vs[buf][row * 64 + fc1]);
        }
        av[4][0] = *(const short8*)(&Ones[llo * 64 + fc0]);
        av[4][1] = *(const short8*)(&Ones[llo * 64 + fc1]);
        short8 bpf[2];
        #pragma unroll
        for (int kh = 0; kh < 2; ++kh)
            bpf[kh] = *(const short8*)(&Ps[w * 16 + llo][kh * 32 + hi * 8]);
        #pragma unroll
        for (int nt2 = 0; nt2 < 5; ++nt2)
            #pragma unroll
            for (int kh = 0; kh < 2; ++kh)
                Oa[nt2] = __builtin_amdgcn_mfma_f32_16x16x32_bf16(
                    av[nt2][kh], bpf[kh], Oa[nt2], 0, 0, 0);
    }

    {
        float lb = __shfl(Oa[4][0], llo);
        float inv = 1.0f / lb;
        #pragma unroll
        for (int nt2 = 0; nt2 < 4; ++nt2) {
            uint2 u;
            u.x = pk2bf(Oa[nt2][0] * inv, Oa[nt2][1] * inv);
            u.y = pk2bf(Oa[nt2][2] * inv, Oa[nt2][3] * inv);
            *(uint2*)(&Ps[w * 16 + llo][nt2 * 16 + hi * 4]) = u;
        }
    }
    __syncthreads();
    #pragma unroll
    for (int p = 0; p < 2; ++p) {
        int idx = tid + 512 * p;
        int r = idx >> 3, cc = idx & 7;
        short8 vv = *(const short8*)(&Ps[r][cc * 8]);
        *(short8*)(attb + ((size_t)(b * T_SEQ + qt * 128 + r)) * C_DIM + h * HD + cc * 8) = vv;
    }
}

__global__ __launch_bounds__(256) void proj_k(
    const short* __restrict__ attb, const short* __restrict__ wpt,
    const float* __restrict__ bp, float* __restrict__ out) {
    const int mt = blockIdx.x, nt_g = blockIdx.y;
    const int m0 = mt * 128, n0 = nt_g * 64;

    __shared__ short As[8192];
    __shared__ short Bs[4096];

    const int tid = threadIdx.x;
    const int lane = tid & 63, w = tid >> 6;
    const int hi = lane >> 4, llo = lane & 15;
    const int lrow = lane >> 3;
    const int lswz = ((lane & 7) ^ (lrow & 7)) * 8;
    const int fc0 = (hi ^ (llo & 7)) * 8;
    const int fc1 = ((hi + 4) ^ (llo & 7)) * 8;

    floatx4 acc[2][4];
    #pragma unroll
    for (int i = 0; i < 2; ++i)
        #pragma unroll
        for (int j = 0; j < 4; ++j)
            #pragma unroll
            for (int r = 0; r < 4; ++r) acc[i][j][r] = 0.0f;

    const size_t a_base = (size_t)(m0 + w * 32 + lrow) * C_DIM + lswz;
    const size_t b_base = (size_t)(n0 + w * 16 + lrow) * C_DIM + lswz;

    for (int kt = 0; kt < C_DIM / 64; ++kt) {
        const int c0 = kt * 64;
        __syncthreads();
        #pragma unroll
        for (int p = 0; p < 4; ++p)
            gld16(attb + a_base + (size_t)p * 8 * C_DIM + c0, &As[(w * 32 + p * 8) * 64]);
        #pragma unroll
        for (int p = 0; p < 2; ++p)
            gld16(wpt + b_base + (size_t)p * 8 * C_DIM + c0, &Bs[(w * 16 + p * 8) * 64]);
        __syncthreads();

        short8 af[2][2];
        #pragma unroll
        for (int m2 = 0; m2 < 2; ++m2) {
            const int row = w * 32 + m2 * 16 + llo;
            af[m2][0] = *(const short8*)(&As[row * 64 + fc0]);
            af[m2][1] = *(const short8*)(&As[row * 64 + fc1]);
        }
        #pragma unroll
        for (int nt = 0; nt < 4; ++nt) {
            const int row = nt * 16 + llo;
            short8 b0 = *(const short8*)(&Bs[row * 64 + fc0]);
            short8 b1 = *(const short8*)(&Bs[row * 64 + fc1]);
            #pragma unroll
            for (int m2 = 0; m2 < 2; ++m2) {
                acc[m2][nt] = __builtin_amdgcn_mfma_f32_16x16x32_bf16(af[m2][0], b0, acc[m2][nt], 0, 0, 0);
                acc[m2][nt] = __builtin_amdgcn_mfma_f32_16x16x32_bf16(af[m2][1], b1, acc[m2][nt], 0, 0, 0);
            }
        }
    }

    #pragma unroll
    for (int nt = 0; nt < 4; ++nt) {
        const int n = n0 + nt * 16 + llo;
        const float bias = bp[n];
        #pragma unroll
        for (int m2 = 0; m2 < 2; ++m2)
            #pragma unroll
            for (int r = 0; r < 4; ++r) {
                int m = m0 + w * 32 + m2 * 16 + hi * 4 + r;
                out[(size_t)m * C_DIM + n] = acc[m2][nt][r] + bias;
            }
    }
}

// ---------------------------------------------------------------------------
extern "C" void kernel_launch(void* const* d_in, const int* in_sizes, int n_in,
                              void* d_out, int out_size, void* d_ws, size_t ws_size,
                              hipStream_t stream) {
    const float* x  = (const float*)d_in[0];
    const float* Wq = (const float*)d_in[1];
    const float* Wk = (const float*)d_in[2];
    const float* Wv = (const float*)d_in[3];
    const float* Wp = (const float*)d_in[4];
    const float* bp = (const float*)d_in[5];
    float* out = (float*)d_out;

    short* xb   = (short*)d_ws;
    short* wt   = xb  + (size_t)M_TOT * C_DIM;
    short* wpt  = wt  + (size_t)3 * H_NUM * HD * C_DIM;
    short* qb   = wpt + (size_t)C_DIM * C_DIM;
    short* kb   = qb  + (size_t)M_TOT * C_DIM;
    short* vtb  = kb  + (size_t)M_TOT * C_DIM;
    short* attb = vtb + (size_t)M_TOT * C_DIM;

    // try cooperative mega-kernel with an occupancy-derived grid
    int maxBlk = 0;
    hipError_t qe = hipOccupancyMaxActiveBlocksPerMultiprocessor(&maxBlk, mega, 512, 0);
    int gridN = 256;
    if (qe == hipSuccess && maxBlk >= 2) gridN = 512;

    void* args[] = { (void*)&x, (void*)&Wq, (void*)&Wk, (void*)&Wv,
                     (void*)&Wp, (void*)&bp,
                     (void*)&xb, (void*)&wt, (void*)&wpt,
                     (void*)&qb, (void*)&kb, (void*)&vtb, (void*)&attb,
                     (void*)&out };
    hipError_t le = hipErrorUnknown;
    if (qe == hipSuccess && maxBlk >= 1)
        le = hipLaunchCooperativeKernel((void*)mega, dim3(gridN), dim3(512),
                                        args, 0, stream);
    if (le != hipSuccess) {
        (void)hipGetLastError();   // clear error state
        prep_k<<<dim3(3072), 256, 0, stream>>>(x, Wq, Wk, Wv, Wp, xb, wt, wpt);
        qkv_k <<<dim3(M_TOT / 128, 3 * C_DIM / 128), 256, 0, stream>>>(xb, wt, qb, kb, vtb);
        attn_k<<<dim3(BH_N, T_SEQ / 128), 512, 0, stream>>>(qb, kb, vtb, attb);
        proj_k<<<dim3(M_TOT / 128, C_DIM / 64), 256, 0, stream>>>(attb, wpt, bp, out);
    }
}

// Round 10
// 178.237 us; speedup vs baseline: 1.7517x; 1.7517x over previous
//
#include <hip/hip_runtime.h>
#include <hip/hip_bf16.h>
#include <hip/hip_cooperative_groups.h>

namespace cg = cooperative_groups;

#define B_NUM 2
#define T_SEQ 2048
#define C_DIM 1024
#define H_NUM 16
#define HD    64
#define M_TOT 4096
#define BH_N  32

typedef __attribute__((ext_vector_type(8))) short short8;   // 8 bf16
typedef __attribute__((ext_vector_type(4))) float floatx4;  // 4 fp32 acc

__device__ __forceinline__ short f2bf(float f) {
    unsigned u = __float_as_uint(f);
    u += 0x7FFFu + ((u >> 16) & 1u);
    return (short)(u >> 16);
}

__device__ __forceinline__ unsigned pk2bf(float a, float b) {
    float2 f2; f2.x = a; f2.y = b;
    __hip_bfloat162 h = __float22bfloat162_rn(f2);
    unsigned u; __builtin_memcpy(&u, &h, 4); return u;
}

// async global->LDS, 16B per lane; LDS dest = wave-uniform base + lane*16
__device__ __forceinline__ void gld16(const short* g, short* l) {
    __builtin_amdgcn_global_load_lds(
        (const __attribute__((address_space(1))) void*)g,
        (__attribute__((address_space(3))) void*)l, 16, 0, 0);
}

// ===========================================================================
// Cooperative mega-kernel (grid-stride phases; works for any grid size).
// launch_bounds(512, 2): VGPR cap 256 -> no spills (round-8 failure was
// (512,4) forcing 64 VGPRs -> ~72 MB scratch spill traffic).
// ===========================================================================
__global__ __launch_bounds__(512, 2) void mega(
    const float* __restrict__ x,  const float* __restrict__ Wq,
    const float* __restrict__ Wk, const float* __restrict__ Wv,
    const float* __restrict__ Wp, const float* __restrict__ bp,
    short* __restrict__ xb, short* __restrict__ wt, short* __restrict__ wpt,
    short* __restrict__ qb, short* __restrict__ kb, short* __restrict__ vtb,
    short* __restrict__ attb, float* __restrict__ out) {

    __shared__ short smem[26112];            // 52224 B, max over phases
    cg::grid_group grid = cg::this_grid();

    const int G   = gridDim.x;
    const int bid = blockIdx.x;
    const int tid = threadIdx.x;
    const int lane = tid & 63, w = tid >> 6;           // 8 waves
    const int hi = lane >> 4, llo = lane & 15;
    const int lrow = lane >> 3;
    const int lswz = ((lane & 7) ^ (lrow & 7)) * 8;
    const int fc0 = (hi ^ (llo & 7)) * 8;
    const int fc1 = ((hi + 4) ^ (llo & 7)) * 8;

    // ============================ Phase 0: prep ============================
    {
        int gtid = bid * 512 + tid;
        for (int i = gtid; i < 524288; i += G * 512) {
            int idx = i * 8;
            float4 a = *(const float4*)(x + idx);
            float4 b4 = *(const float4*)(x + idx + 4);
            short8 o;
            o[0] = f2bf(a.x);  o[1] = f2bf(a.y);  o[2] = f2bf(a.z);  o[3] = f2bf(a.w);
            o[4] = f2bf(b4.x); o[5] = f2bf(b4.y); o[6] = f2bf(b4.z); o[7] = f2bf(b4.w);
            *(short8*)(xb + idx) = o;
        }
        short (*sh)[72] = (short(*)[72])smem;
        for (int unit = bid; unit < 1024; unit += G) {
            __syncthreads();
            if (unit < 768) {
                const int y = unit >> 4, ct = unit & 15;
                const int which = y >> 4, h = y & 15;
                const float* W = ((which == 0) ? Wq : (which == 1) ? Wk : Wv)
                                 + (size_t)h * C_DIM * HD;
                const int c0 = ct * 64;
                #pragma unroll
                for (int p = 0; p < 2; ++p) {
                    int idx = tid + 512 * p;
                    int c = idx >> 4, d4 = idx & 15;
                    float4 v = *(const float4*)(W + (size_t)(c0 + c) * HD + d4 * 4);
                    sh[d4 * 4 + 0][c] = f2bf(v.x);
                    sh[d4 * 4 + 1][c] = f2bf(v.y);
                    sh[d4 * 4 + 2][c] = f2bf(v.z);
                    sh[d4 * 4 + 3][c] = f2bf(v.w);
                }
                __syncthreads();
                int d = tid >> 3, cc = tid & 7;
                short8 vv = *(const short8*)(&sh[d][cc * 8]);
                *(short8*)(wt + ((size_t)(which * 16 + h) * 64 + d) * C_DIM + c0 + cc * 8) = vv;
            } else {
                const int u2 = unit - 768;
                const int nt = u2 >> 4, ct = u2 & 15;
                #pragma unroll
                for (int p = 0; p < 2; ++p) {
                    int idx = tid + 512 * p;
                    int k = idx >> 4, n4 = idx & 15;
                    float4 v = *(const float4*)(Wp + (size_t)(ct * 64 + k) * C_DIM + nt * 64 + n4 * 4);
                    sh[n4 * 4 + 0][k] = f2bf(v.x);
                    sh[n4 * 4 + 1][k] = f2bf(v.y);
                    sh[n4 * 4 + 2][k] = f2bf(v.z);
                    sh[n4 * 4 + 3][k] = f2bf(v.w);
                }
                __syncthreads();
                int n = tid >> 3, cc = tid & 7;
                short8 vv = *(const short8*)(&sh[n][cc * 8]);
                *(short8*)(wpt + (size_t)(nt * 64 + n) * C_DIM + ct * 64 + cc * 8) = vv;
            }
        }
    }
    grid.sync();

    // ============================ Phase 1: qkv =============================
    // C[4096 x 3072] = xb * wt^T. 512 tiles of 128 x 192, BK=64.
    for (int tile = bid; tile < 512; tile += G) {
        const int mt = tile >> 4, ntg = tile & 15;
        const int m0 = mt * 128, n0 = ntg * 192;
        const int wm = w & 1, wn = w >> 1;
        short* As = smem;                    // [128][64] swizzled
        short* Bs = smem + 8192;             // [192][64] swizzled

        floatx4 acc[4][3];
        #pragma unroll
        for (int i = 0; i < 4; ++i)
            #pragma unroll
            for (int j = 0; j < 3; ++j)
                #pragma unroll
                for (int r = 0; r < 4; ++r) acc[i][j][r] = 0.0f;

        const size_t a_base = (size_t)(m0 + w * 16 + lrow) * C_DIM + lswz;
        const size_t b_base = (size_t)(n0 + w * 24 + lrow) * C_DIM + lswz;

        for (int kt = 0; kt < C_DIM / 64; ++kt) {
            const int c0 = kt * 64;
            __syncthreads();
            #pragma unroll
            for (int p = 0; p < 2; ++p)
                gld16(xb + a_base + (size_t)p * 8 * C_DIM + c0, &As[(w * 16 + p * 8) * 64]);
            #pragma unroll
            for (int p = 0; p < 3; ++p)
                gld16(wt + b_base + (size_t)p * 8 * C_DIM + c0, &Bs[(w * 24 + p * 8) * 64]);
            __syncthreads();

            short8 af[4][2];
            #pragma unroll
            for (int mi = 0; mi < 4; ++mi) {
                const int row = wm * 64 + mi * 16 + llo;
                af[mi][0] = *(const short8*)(&As[row * 64 + fc0]);
                af[mi][1] = *(const short8*)(&As[row * 64 + fc1]);
            }
            #pragma unroll
            for (int ni = 0; ni < 3; ++ni) {
                const int row = wn * 48 + ni * 16 + llo;
                short8 b0 = *(const short8*)(&Bs[row * 64 + fc0]);
                short8 b1 = *(const short8*)(&Bs[row * 64 + fc1]);
                #pragma unroll
                for (int mi = 0; mi < 4; ++mi) {
                    acc[mi][ni] = __builtin_amdgcn_mfma_f32_16x16x32_bf16(af[mi][0], b0, acc[mi][ni], 0, 0, 0);
                    acc[mi][ni] = __builtin_amdgcn_mfma_f32_16x16x32_bf16(af[mi][1], b1, acc[mi][ni], 0, 0, 0);
                }
            }
        }

        const int bb = m0 >> 11;
        #pragma unroll
        for (int c = 0; c < 3; ++c) {
            const int n_chunk = n0 + 64 * c;
            const int which = n_chunk >> 10;
            const int h = (n_chunk >> 6) & 15;
            __syncthreads();
            if (which == 2) {
                short (*R)[136] = (short(*)[136])smem;
                #pragma unroll
                for (int ni = 0; ni < 3; ++ni) {
                    const int gcol = wn * 48 + ni * 16;
                    if ((gcol >> 6) == c) {
                        #pragma unroll
                        for (int mi = 0; mi < 4; ++mi)
                            #pragma unroll
                            for (int r = 0; r < 4; ++r)
                                R[(gcol & 63) + llo][wm * 64 + mi * 16 + hi * 4 + r] =
                                    f2bf(acc[mi][ni][r]);
                    }
                }
                __syncthreads();
                #pragma unroll
                for (int p = 0; p < 2; ++p) {
                    int idx = tid + 512 * p;
                    int rr = idx >> 4, cc = idx & 15;
                    short8 vv = *(const short8*)(&R[rr][cc * 8]);
                    int t = (m0 & 2047) + cc * 8;
                    *(short8*)(vtb + ((size_t)((bb * H_NUM + h) * HD + rr)) * T_SEQ + t) = vv;
                }
            } else {
                short (*R)[72] = (short(*)[72])smem;
                const float scl = (which == 0) ? 0.125f * 1.4426950408889634f : 1.0f;
                #pragma unroll
                for (int ni = 0; ni < 3; ++ni) {
                    const int gcol = wn * 48 + ni * 16;
                    if ((gcol >> 6) == c) {
                        #pragma unroll
                        for (int mi = 0; mi < 4; ++mi)
                            #pragma unroll
                            for (int r = 0; r < 4; ++r)
                                R[wm * 64 + mi * 16 + hi * 4 + r][(gcol & 63) + llo] =
                                    f2bf(acc[mi][ni][r] * scl);
                    }
                }
                __syncthreads();
                short* outp = (which == 0) ? qb : kb;
                #pragma unroll
                for (int p = 0; p < 2; ++p) {
                    int idx = tid + 512 * p;
                    int r = idx >> 3, cc = idx & 7;
                    short8 vv = *(const short8*)(&R[r][cc * 8]);
                    int t = (m0 + r) & 2047;
                    *(short8*)(outp + ((size_t)(bb * H_NUM + h) * T_SEQ + t) * HD + cc * 8) = vv;
                }
            }
        }
    }
    grid.sync();

    // ============================ Phase 2: attn ============================
    for (int unit = bid; unit < 512; unit += G) {
        const int bh = unit & 31;
        const int y = unit >> 5;
        const int qt = (y < 8) ? (15 - y) : (y - 8);
        const int b = bh >> 4, h = bh & 15;
        const short* K  = kb  + (size_t)bh * T_SEQ * HD;
        const short* Vt = vtb + (size_t)bh * HD * T_SEQ;

        short* Ks = smem;                    // [2][64][64] swizzled (8192 shorts)
        short* Vs = smem + 8192;
        short (*Ps)[76] = (short(*)[76])(smem + 16384);  // [128][76]

        const int kmax = 2 * qt + 1;

        short8 qf[2];
        const int qcol0 = qt * 128 + w * 16;
        #pragma unroll
        for (int kh = 0; kh < 2; ++kh)
            qf[kh] = *(const short8*)(qb +
                ((size_t)bh * T_SEQ + qcol0 + llo) * HD + kh * 32 + hi * 8);

        short8 av4;                          // ones-row A-frag
        #pragma unroll
        for (int j = 0; j < 8; ++j) av4[j] = (llo == 0) ? (short)0x3F80 : (short)0;

        gld16(K + (size_t)(w * 8 + lrow) * HD + lswz, &Ks[(w * 8) * 64]);
        gld16(Vt + (size_t)(w * 8 + lrow) * T_SEQ + lswz, &Vs[(w * 8) * 64]);

        floatx4 Oa[5];
        #pragma unroll
        for (int n = 0; n < 5; ++n)
            #pragma unroll
            for (int r = 0; r < 4; ++r) Oa[n][r] = 0.0f;

        for (int kt = 0; kt <= kmax; ++kt) {
            __syncthreads();
            const int buf = (kt & 1) * 4096;

            if (kt + 1 <= kmax) {
                const int s0 = (kt + 1) * 64;
                const int nb = ((kt + 1) & 1) * 4096;
                gld16(K + ((size_t)s0 + w * 8 + lrow) * HD + lswz, &Ks[nb + (w * 8) * 64]);
                gld16(Vt + (size_t)(w * 8 + lrow) * T_SEQ + s0 + lswz, &Vs[nb + (w * 8) * 64]);
            }

            short8 ak[4][2];
            #pragma unroll
            for (int nt = 0; nt < 4; ++nt) {
                const int row = nt * 16 + llo;
                ak[nt][0] = *(const short8*)(&Ks[buf + row * 64 + fc0]);
                ak[nt][1] = *(const short8*)(&Ks[buf + row * 64 + fc1]);
            }
            floatx4 sf[4];
            #pragma unroll
            for (int nt = 0; nt < 4; ++nt)
                #pragma unroll
                for (int r = 0; r < 4; ++r) sf[nt][r] = 0.0f;
            #pragma unroll
            for (int nt = 0; nt < 4; ++nt)
                #pragma unroll
                for (int kh = 0; kh < 2; ++kh)
                    sf[nt] = __builtin_amdgcn_mfma_f32_16x16x32_bf16(
                        ak[nt][kh], qf[kh], sf[nt], 0, 0, 0);

            const int sbase = kt * 64;
            if (sbase + 63 > qcol0) {
                const int qlane = qcol0 + llo;
                #pragma unroll
                for (int nt = 0; nt < 4; ++nt)
                    #pragma unroll
                    for (int r = 0; r < 4; ++r)
                        if (sbase + nt * 16 + hi * 4 + r > qlane) sf[nt][r] = -3.0e38f;
            }

            #pragma unroll
            for (int nt = 0; nt < 4; ++nt) {
                float p0 = __builtin_amdgcn_exp2f(sf[nt][0]);
                float p1 = __builtin_amdgcn_exp2f(sf[nt][1]);
                float p2 = __builtin_amdgcn_exp2f(sf[nt][2]);
                float p3 = __builtin_amdgcn_exp2f(sf[nt][3]);
                uint2 u; u.x = pk2bf(p0, p1); u.y = pk2bf(p2, p3);
                *(uint2*)(&Ps[w * 16 + llo][nt * 16 + hi * 4]) = u;
            }

            short8 av[5][2];
            #pragma unroll
            for (int nt2 = 0; nt2 < 4; ++nt2) {
                const int row = nt2 * 16 + llo;
                av[nt2][0] = *(const short8*)(&Vs[buf + row * 64 + fc0]);
                av[nt2][1] = *(const short8*)(&Vs[buf + row * 64 + fc1]);
            }
            av[4][0] = av4;
            av[4][1] = av4;
            short8 bpf[2];
            #pragma unroll
            for (int kh = 0; kh < 2; ++kh)
                bpf[kh] = *(const short8*)(&Ps[w * 16 + llo][kh * 32 + hi * 8]);
            #pragma unroll
            for (int nt2 = 0; nt2 < 5; ++nt2)
                #pragma unroll
                for (int kh = 0; kh < 2; ++kh)
                    Oa[nt2] = __builtin_amdgcn_mfma_f32_16x16x32_bf16(
                        av[nt2][kh], bpf[kh], Oa[nt2], 0, 0, 0);
        }

        {
            float lb = __shfl(Oa[4][0], llo);
            float inv = 1.0f / lb;
            #pragma unroll
            for (int nt2 = 0; nt2 < 4; ++nt2) {
                uint2 u;
                u.x = pk2bf(Oa[nt2][0] * inv, Oa[nt2][1] * inv);
                u.y = pk2bf(Oa[nt2][2] * inv, Oa[nt2][3] * inv);
                *(uint2*)(&Ps[w * 16 + llo][nt2 * 16 + hi * 4]) = u;
            }
        }
        __syncthreads();
        #pragma unroll
        for (int p = 0; p < 2; ++p) {
            int idx = tid + 512 * p;
            int r = idx >> 3, cc = idx & 7;
            short8 vv = *(const short8*)(&Ps[r][cc * 8]);
            *(short8*)(attb + ((size_t)(b * T_SEQ + qt * 128 + r)) * C_DIM + h * HD + cc * 8) = vv;
        }
        __syncthreads();
    }
    grid.sync();

    // ============================ Phase 3: proj ============================
    for (int tile = bid; tile < 512; tile += G) {
        const int mt = tile >> 4, ntg = tile & 15;
        const int m0 = mt * 128, n0 = ntg * 64;
        const int wm = w & 1, wn = w >> 1;
        short* As = smem;                    // [128][64] swizzled
        short* Bs = smem + 8192;             // [64][64]  swizzled

        floatx4 acc[4];
        #pragma unroll
        for (int i = 0; i < 4; ++i)
            #pragma unroll
            for (int r = 0; r < 4; ++r) acc[i][r] = 0.0f;

        const size_t a_base = (size_t)(m0 + w * 16 + lrow) * C_DIM + lswz;
        const size_t b_base = (size_t)(n0 + w * 8 + lrow) * C_DIM + lswz;

        for (int kt = 0; kt < C_DIM / 64; ++kt) {
            const int c0 = kt * 64;
            __syncthreads();
            #pragma unroll
            for (int p = 0; p < 2; ++p)
                gld16(attb + a_base + (size_t)p * 8 * C_DIM + c0, &As[(w * 16 + p * 8) * 64]);
            gld16(wpt + b_base + c0, &Bs[(w * 8) * 64]);
            __syncthreads();

            short8 af[4][2];
            #pragma unroll
            for (int mi = 0; mi < 4; ++mi) {
                const int row = wm * 64 + mi * 16 + llo;
                af[mi][0] = *(const short8*)(&As[row * 64 + fc0]);
                af[mi][1] = *(const short8*)(&As[row * 64 + fc1]);
            }
            const int brow = wn * 16 + llo;
            short8 b0 = *(const short8*)(&Bs[brow * 64 + fc0]);
            short8 b1 = *(const short8*)(&Bs[brow * 64 + fc1]);
            #pragma unroll
            for (int mi = 0; mi < 4; ++mi) {
                acc[mi] = __builtin_amdgcn_mfma_f32_16x16x32_bf16(af[mi][0], b0, acc[mi], 0, 0, 0);
                acc[mi] = __builtin_amdgcn_mfma_f32_16x16x32_bf16(af[mi][1], b1, acc[mi], 0, 0, 0);
            }
        }

        const int n = n0 + wn * 16 + llo;
        const float bias = bp[n];
        #pragma unroll
        for (int mi = 0; mi < 4; ++mi)
            #pragma unroll
            for (int r = 0; r < 4; ++r) {
                int m = m0 + wm * 64 + mi * 16 + hi * 4 + r;
                out[(size_t)m * C_DIM + n] = acc[mi][r] + bias;
            }
        __syncthreads();
    }
}

// ===========================================================================
// Fallback path: round-6 four-kernel pipeline (known-good, ~179 us).
// ===========================================================================
__global__ __launch_bounds__(256) void prep_k(
    const float* __restrict__ x, const float* __restrict__ Wq,
    const float* __restrict__ Wk, const float* __restrict__ Wv,
    const float* __restrict__ Wp,
    short* __restrict__ xb, short* __restrict__ wt, short* __restrict__ wpt) {
    const int bid = blockIdx.x;
    const int tid = threadIdx.x;
    if (bid < 2048) {
        int idx = (bid * 256 + tid) * 8;
        float4 a = *(const float4*)(x + idx);
        float4 b = *(const float4*)(x + idx + 4);
        short8 o;
        o[0] = f2bf(a.x); o[1] = f2bf(a.y); o[2] = f2bf(a.z); o[3] = f2bf(a.w);
        o[4] = f2bf(b.x); o[5] = f2bf(b.y); o[6] = f2bf(b.z); o[7] = f2bf(b.w);
        *(short8*)(xb + idx) = o;
        return;
    }
    const int b2 = bid - 2048;
    const int ct = b2 & 15, y = b2 >> 4;
    __shared__ short sh[64][72];
    if (y < 48) {
        const int which = y >> 4, h = y & 15;
        const float* W = ((which == 0) ? Wq : (which == 1) ? Wk : Wv) + (size_t)h * C_DIM * HD;
        const int c0 = ct * 64;
        #pragma unroll
        for (int p = 0; p < 4; ++p) {
            int idx = tid + 256 * p;
            int c = idx >> 4, d4 = idx & 15;
            float4 v = *(const float4*)(W + (size_t)(c0 + c) * HD + d4 * 4);
            sh[d4 * 4 + 0][c] = f2bf(v.x);
            sh[d4 * 4 + 1][c] = f2bf(v.y);
            sh[d4 * 4 + 2][c] = f2bf(v.z);
            sh[d4 * 4 + 3][c] = f2bf(v.w);
        }
        __syncthreads();
        #pragma unroll
        for (int p = 0; p < 2; ++p) {
            int idx = tid + 256 * p;
            int d = idx >> 3, cc = idx & 7;
            short8 vv = *(const short8*)(&sh[d][cc * 8]);
            *(short8*)(wt + ((size_t)(which * 16 + h) * 64 + d) * C_DIM + c0 + cc * 8) = vv;
        }
    } else {
        const int nt = y - 48;
        #pragma unroll
        for (int p = 0; p < 4; ++p) {
            int idx = tid + 256 * p;
            int k = idx >> 4, n4 = idx & 15;
            float4 v = *(const float4*)(Wp + (size_t)(ct * 64 + k) * C_DIM + nt * 64 + n4 * 4);
            sh[n4 * 4 + 0][k] = f2bf(v.x);
            sh[n4 * 4 + 1][k] = f2bf(v.y);
            sh[n4 * 4 + 2][k] = f2bf(v.z);
            sh[n4 * 4 + 3][k] = f2bf(v.w);
        }
        __syncthreads();
        #pragma unroll
        for (int p = 0; p < 2; ++p) {
            int idx = tid + 256 * p;
            int n = idx >> 3, cc = idx & 7;
            short8 vv = *(const short8*)(&sh[n][cc * 8]);
            *(short8*)(wpt + (size_t)(nt * 64 + n) * C_DIM + ct * 64 + cc * 8) = vv;
        }
    }
}

__global__ __launch_bounds__(256) void qkv_k(
    const short* __restrict__ xb, const short* __restrict__ wt,
    short* __restrict__ qb, short* __restrict__ kb, short* __restrict__ vtb) {
    const int mt = blockIdx.x, ntg = blockIdx.y;
    const int m0 = mt * 128, n0 = ntg * 128;
    const int which = ntg >> 3;
    const float sc = (which == 0) ? 0.125f * 1.4426950408889634f : 1.0f;

    __shared__ short smem[17408];
    short* As = smem;
    short* Bs = smem + 8192;

    const int tid = threadIdx.x;
    const int lane = tid & 63, w = tid >> 6;
    const int wm = w & 1, wn = w >> 1;
    const int hi = lane >> 4, llo = lane & 15;
    const int lrow = lane >> 3;
    const int lswz = ((lane & 7) ^ (lrow & 7)) * 8;
    const int fc0 = (hi ^ (llo & 7)) * 8;
    const int fc1 = ((hi + 4) ^ (llo & 7)) * 8;

    floatx4 acc[4][4];
    #pragma unroll
    for (int i = 0; i < 4; ++i)
        #pragma unroll
        for (int j = 0; j < 4; ++j)
            #pragma unroll
            for (int r = 0; r < 4; ++r) acc[i][j][r] = 0.0f;

    const size_t a_base = (size_t)(m0 + w * 32 + lrow) * C_DIM + lswz;
    const size_t b_base = (size_t)(n0 + w * 32 + lrow) * C_DIM + lswz;

    for (int kt = 0; kt < C_DIM / 64; ++kt) {
        const int c0 = kt * 64;
        __syncthreads();
        #pragma unroll
        for (int p = 0; p < 4; ++p) {
            gld16(xb + a_base + (size_t)p * 8 * C_DIM + c0, &As[(w * 32 + p * 8) * 64]);
            gld16(wt + b_base + (size_t)p * 8 * C_DIM + c0, &Bs[(w * 32 + p * 8) * 64]);
        }
        __syncthreads();

        short8 af[4][2];
        #pragma unroll
        for (int mi = 0; mi < 4; ++mi) {
            const int row = wm * 64 + mi * 16 + llo;
            af[mi][0] = *(const short8*)(&As[row * 64 + fc0]);
            af[mi][1] = *(const short8*)(&As[row * 64 + fc1]);
        }
        #pragma unroll
        for (int ni = 0; ni < 4; ++ni) {
            const int row = wn * 64 + ni * 16 + llo;
            short8 b0 = *(const short8*)(&Bs[row * 64 + fc0]);
            short8 b1 = *(const short8*)(&Bs[row * 64 + fc1]);
            #pragma unroll
            for (int mi = 0; mi < 4; ++mi) {
                acc[mi][ni] = __builtin_amdgcn_mfma_f32_16x16x32_bf16(af[mi][0], b0, acc[mi][ni], 0, 0, 0);
                acc[mi][ni] = __builtin_amdgcn_mfma_f32_16x16x32_bf16(af[mi][1], b1, acc[mi][ni], 0, 0, 0);
            }
        }
    }
    __syncthreads();

    short (*R)[136] = (short(*)[136])smem;
    if (which == 2) {
        #pragma unroll
        for (int mi = 0; mi < 4; ++mi)
            #pragma unroll
            for (int ni = 0; ni < 4; ++ni)
                #pragma unroll
                for (int r = 0; r < 4; ++r)
                    R[wn * 64 + ni * 16 + llo][wm * 64 + mi * 16 + hi * 4 + r] =
                        f2bf(acc[mi][ni][r]);
        __syncthreads();
        const int b = m0 >> 11;
        #pragma unroll
        for (int p = 0; p < 8; ++p) {
            int idx = tid + 256 * p;
            int rr = idx >> 4, cc = idx & 15;
            short8 vv = *(const short8*)(&R[rr][cc * 8]);
            int n = n0 + rr;
            int h = (n >> 6) & 15, d = n & 63;
            int t = (m0 & 2047) + cc * 8;
            *(short8*)(vtb + ((size_t)((b * H_NUM + h) * HD + d)) * T_SEQ + t) = vv;
        }
    } else {
        short* outp = (which == 0) ? qb : kb;
        #pragma unroll
        for (int mi = 0; mi < 4; ++mi)
            #pragma unroll
            for (int ni = 0; ni < 4; ++ni)
                #pragma unroll
                for (int r = 0; r < 4; ++r)
                    R[wm * 64 + mi * 16 + hi * 4 + r][wn * 64 + ni * 16 + llo] =
                        f2bf(acc[mi][ni][r] * sc);
        __syncthreads();
        #pragma unroll
        for (int p = 0; p < 8; ++p) {
            int idx = tid + 256 * p;
            int r = idx >> 4, cc = idx & 15;
            short8 vv = *(const short8*)(&R[r][cc * 8]);
            int mg = m0 + r;
            int b = mg >> 11, t = mg & 2047;
            int n = n0 + cc * 8;
            int h = (n >> 6) & 15, d = n & 63;
            *(short8*)(outp + ((size_t)(b * H_NUM + h) * T_SEQ + t) * HD + d) = vv;
        }
    }
}

__global__ __launch_bounds__(512) void attn_k(
    const short* __restrict__ qb, const short* __restrict__ kb,
    const short* __restrict__ vtb, short* __restrict__ attb) {
    const int bh = blockIdx.x;
    const int y = blockIdx.y;
    const int qt = (y < 8) ? (15 - y) : (y - 8);
    const int b = bh >> 4, h = bh & 15;
    const short* K  = kb  + (size_t)bh * T_SEQ * HD;
    const short* Vt = vtb + (size_t)bh * HD * T_SEQ;

    __shared__ short Ks[2][4096];
    __shared__ short Vs[2][4096];
    __shared__ short Ones[16 * 64];
    __shared__ short Ps[128][76];

    const int tid = threadIdx.x;
    const int lane = tid & 63, w = tid >> 6;
    const int hi = lane >> 4, llo = lane & 15;
    const int lrow = lane >> 3;
    const int lswz = ((lane & 7) ^ (lrow & 7)) * 8;
    const int fc0 = (hi ^ (llo & 7)) * 8;
    const int fc1 = ((hi + 4) ^ (llo & 7)) * 8;
    const int kmax = 2 * qt + 1;

    short8 qf[2];
    const int qcol0 = qt * 128 + w * 16;
    #pragma unroll
    for (int kh = 0; kh < 2; ++kh)
        qf[kh] = *(const short8*)(qb +
            ((size_t)bh * T_SEQ + qcol0 + llo) * HD + kh * 32 + hi * 8);

    for (int i = tid; i < 16 * 64; i += 512)
        Ones[i] = (i < 64) ? (short)0x3F80 : (short)0;

    gld16(K + (size_t)(w * 8 + lrow) * HD + lswz, &Ks[0][(w * 8) * 64]);
    gld16(Vt + (size_t)(w * 8 + lrow) * T_SEQ + lswz, &Vs[0][(w * 8) * 64]);

    floatx4 Oa[5];
    #pragma unroll
    for (int n = 0; n < 5; ++n)
        #pragma unroll
        for (int r = 0; r < 4; ++r) Oa[n][r] = 0.0f;

    for (int kt = 0; kt <= kmax; ++kt) {
        __syncthreads();
        const int buf = kt & 1;

        if (kt + 1 <= kmax) {
            const int s0 = (kt + 1) * 64;
            const int nb = buf ^ 1;
            gld16(K + ((size_t)s0 + w * 8 + lrow) * HD + lswz, &Ks[nb][(w * 8) * 64]);
            gld16(Vt + (size_t)(w * 8 + lrow) * T_SEQ + s0 + lswz, &Vs[nb][(w * 8) * 64]);
        }

        short8 ak[4][2];
        #pragma unroll
        for (int nt = 0; nt < 4; ++nt) {
            const int row = nt * 16 + llo;
            ak[nt][0] = *(const short8*)(&Ks[buf][row * 64 + fc0]);
            ak[nt][1] = *(const short8*)(&Ks[buf][row * 64 + fc1]);
        }
        floatx4 sf[4];
        #pragma unroll
        for (int nt = 0; nt < 4; ++nt)
            #pragma unroll
            for (int r = 0; r < 4; ++r) sf[nt][r] = 0.0f;
        #pragma unroll
        for (int nt = 0; nt < 4; ++nt)
            #pragma unroll
            for (int kh = 0; kh < 2; ++kh)
                sf[nt] = __builtin_amdgcn_mfma_f32_16x16x32_bf16(
                    ak[nt][kh], qf[kh], sf[nt], 0, 0, 0);

        const int sbase = kt * 64;
        if (sbase + 63 > qcol0) {
            const int qlane = qcol0 + llo;
            #pragma unroll
            for (int nt = 0; nt < 4; ++nt)
                #pragma unroll
                for (int r = 0; r < 4; ++r)
                    if (sbase + nt * 16 + hi * 4 + r > qlane) sf[nt][r] = -3.0e38f;
        }

        #pragma unroll
        for (int nt = 0; nt < 4; ++nt) {
            float p0 = __builtin_amdgcn_exp2f(sf[nt][0]);
            float p1 = __builtin_amdgcn_exp2f(sf[nt][1]);
            float p2 = __builtin_amdgcn_exp2f(sf[nt][2]);
            float p3 = __builtin_amdgcn_exp2f(sf[nt][3]);
            uint2 u; u.x = pk2bf(p0, p1); u.y = pk2bf(p2, p3);
            *(uint2*)(&Ps[w * 16 + llo][nt * 16 + hi * 4]) = u;
        }

        short8 av[5][2];
        #pragma unroll
        for (int nt2 = 0; nt2 < 4; ++nt2) {
            const int row = nt2 * 16 + llo;
            av[nt2][0] = *(const short8*)(&Vs[buf][row * 64 + fc0]);
            av[nt2][1] = *(const short8*)(&Vs[buf][row * 64 + fc1]);
        }
        av[4][0] = *(const short8*)(&Ones[llo * 64 + fc0]);
        av[4][1] = *(const short8*)(&Ones[llo * 64 + fc1]);
        short8 bpf[2];
        #pragma unroll
        for (int kh = 0; kh < 2; ++kh)
            bpf[kh] = *(const short8*)(&Ps[w * 16 + llo][kh * 32 + hi * 8]);
        #pragma unroll
        for (int nt2 = 0; nt2 < 5; ++nt2)
            #pragma unroll
            for (int kh = 0; kh < 2; ++kh)
                Oa[nt2] = __builtin_amdgcn_mfma_f32_16x16x32_bf16(
                    av[nt2][kh], bpf[kh], Oa[nt2], 0, 0, 0);
    }

    {
        float lb = __shfl(Oa[4][0], llo);
        float inv = 1.0f / lb;
        #pragma unroll
        for (int nt2 = 0; nt2 < 4; ++nt2) {
            uint2 u;
            u.x = pk2bf(Oa[nt2][0] * inv, Oa[nt2][1] * inv);
            u.y = pk2bf(Oa[nt2][2] * inv, Oa[nt2][3] * inv);
            *(uint2*)(&Ps[w * 16 + llo][nt2 * 16 + hi * 4]) = u;
        }
    }
    __syncthreads();
    #pragma unroll
    for (int p = 0; p < 2; ++p) {
        int idx = tid + 512 * p;
        int r = idx >> 3, cc = idx & 7;
        short8 vv = *(const short8*)(&Ps[r][cc * 8]);
        *(short8*)(attb + ((size_t)(b * T_SEQ + qt * 128 + r)) * C_DIM + h * HD + cc * 8) = vv;
    }
}

__global__ __launch_bounds__(256) void proj_k(
    const short* __restrict__ attb, const short* __restrict__ wpt,
    const float* __restrict__ bp, float* __restrict__ out) {
    const int mt = blockIdx.x, nt_g = blockIdx.y;
    const int m0 = mt * 128, n0 = nt_g * 64;

    __shared__ short As[8192];
    __shared__ short Bs[4096];

    const int tid = threadIdx.x;
    const int lane = tid & 63, w = tid >> 6;
    const int hi = lane >> 4, llo = lane & 15;
    const int lrow = lane >> 3;
    const int lswz = ((lane & 7) ^ (lrow & 7)) * 8;
    const int fc0 = (hi ^ (llo & 7)) * 8;
    const int fc1 = ((hi + 4) ^ (llo & 7)) * 8;

    floatx4 acc[2][4];
    #pragma unroll
    for (int i = 0; i < 2; ++i)
        #pragma unroll
        for (int j = 0; j < 4; ++j)
            #pragma unroll
            for (int r = 0; r < 4; ++r) acc[i][j][r] = 0.0f;

    const size_t a_base = (size_t)(m0 + w * 32 + lrow) * C_DIM + lswz;
    const size_t b_base = (size_t)(n0 + w * 16 + lrow) * C_DIM + lswz;

    for (int kt = 0; kt < C_DIM / 64; ++kt) {
        const int c0 = kt * 64;
        __syncthreads();
        #pragma unroll
        for (int p = 0; p < 4; ++p)
            gld16(attb + a_base + (size_t)p * 8 * C_DIM + c0, &As[(w * 32 + p * 8) * 64]);
        #pragma unroll
        for (int p = 0; p < 2; ++p)
            gld16(wpt + b_base + (size_t)p * 8 * C_DIM + c0, &Bs[(w * 16 + p * 8) * 64]);
        __syncthreads();

        short8 af[2][2];
        #pragma unroll
        for (int m2 = 0; m2 < 2; ++m2) {
            const int row = w * 32 + m2 * 16 + llo;
            af[m2][0] = *(const short8*)(&As[row * 64 + fc0]);
            af[m2][1] = *(const short8*)(&As[row * 64 + fc1]);
        }
        #pragma unroll
        for (int nt = 0; nt < 4; ++nt) {
            const int row = nt * 16 + llo;
            short8 b0 = *(const short8*)(&Bs[row * 64 + fc0]);
            short8 b1 = *(const short8*)(&Bs[row * 64 + fc1]);
            #pragma unroll
            for (int m2 = 0; m2 < 2; ++m2) {
                acc[m2][nt] = __builtin_amdgcn_mfma_f32_16x16x32_bf16(af[m2][0], b0, acc[m2][nt], 0, 0, 0);
                acc[m2][nt] = __builtin_amdgcn_mfma_f32_16x16x32_bf16(af[m2][1], b1, acc[m2][nt], 0, 0, 0);
            }
        }
    }

    #pragma unroll
    for (int nt = 0; nt < 4; ++nt) {
        const int n = n0 + nt * 16 + llo;
        const float bias = bp[n];
        #pragma unroll
        for (int m2 = 0; m2 < 2; ++m2)
            #pragma unroll
            for (int r = 0; r < 4; ++r) {
                int m = m0 + w * 32 + m2 * 16 + hi * 4 + r;
                out[(size_t)m * C_DIM + n] = acc[m2][nt][r] + bias;
            }
    }
}

// ---------------------------------------------------------------------------
extern "C" void kernel_launch(void* const* d_in, const int* in_sizes, int n_in,
                              void* d_out, int out_size, void* d_ws, size_t ws_size,
                              hipStream_t stream) {
    const float* x  = (const float*)d_in[0];
    const float* Wq = (const float*)d_in[1];
    const float* Wk = (const float*)d_in[2];
    const float* Wv = (const float*)d_in[3];
    const float* Wp = (const float*)d_in[4];
    const float* bp = (const float*)d_in[5];
    float* out = (float*)d_out;

    short* xb   = (short*)d_ws;
    short* wt   = xb  + (size_t)M_TOT * C_DIM;
    short* wpt  = wt  + (size_t)3 * H_NUM * HD * C_DIM;
    short* qb   = wpt + (size_t)C_DIM * C_DIM;
    short* kb   = qb  + (size_t)M_TOT * C_DIM;
    short* vtb  = kb  + (size_t)M_TOT * C_DIM;
    short* attb = vtb + (size_t)M_TOT * C_DIM;

    // try cooperative mega-kernel with an occupancy-derived grid
    int maxBlk = 0;
    hipError_t qe = hipOccupancyMaxActiveBlocksPerMultiprocessor(&maxBlk, mega, 512, 0);
    int gridN = 256;
    if (qe == hipSuccess && maxBlk >= 2) gridN = 512;

    void* args[] = { (void*)&x, (void*)&Wq, (void*)&Wk, (void*)&Wv,
                     (void*)&Wp, (void*)&bp,
                     (void*)&xb, (void*)&wt, (void*)&wpt,
                     (void*)&qb, (void*)&kb, (void*)&vtb, (void*)&attb,
                     (void*)&out };
    hipError_t le = hipErrorUnknown;
    if (qe == hipSuccess && maxBlk >= 1)
        le = hipLaunchCooperativeKernel((void*)mega, dim3(gridN), dim3(512),
                                        args, 0, stream);
    if (le != hipSuccess) {
        (void)hipGetLastError();   // clear error state
        prep_k<<<dim3(3072), 256, 0, stream>>>(x, Wq, Wk, Wv, Wp, xb, wt, wpt);
        qkv_k <<<dim3(M_TOT / 128, 3 * C_DIM / 128), 256, 0, stream>>>(xb, wt, qb, kb, vtb);
        attn_k<<<dim3(BH_N, T_SEQ / 128), 512, 0, stream>>>(qb, kb, vtb, attb);
        proj_k<<<dim3(M_TOT / 128, C_DIM / 64), 256, 0, stream>>>(attb, wpt, bp, out);
    }
}